// Round 3
// baseline (1068.349 us; speedup 1.0000x reference)
//
#include <hip/hip_runtime.h>

// B-spline dense scatter, restructured as a fill-shaped kernel.
//
// out[row, col] = value_k(xs[row]) when col == floor(xs[row]) + k (k in 0..3),
// else 0. value_k = Horner(B[k], frac(x) + (3-k)).
//
// Output is 131072 x 2048 f32 = 1 GiB -> pure HBM-write roofline (~170 us at
// 6.2 TB/s, the rate the rocclr fill kernel demonstrates on this chip).
//
// Previous version: 131072 tiny blocks, 2 stores/thread, every store gated on
// the xs[row] load -> latency-churn-bound at ~3.3 TB/s.
// This version: 4096 blocks x 256 threads; each block owns 32 contiguous rows
// (256 KiB). Phase A is a pure dependence-free zero stream (64 independent
// nontemporal 16B stores per thread, identical shape to fillBuffer).
// Phase B (after a barrier that drains vmcnt) scatters the 4 nonzero values
// per row: 2 MiB total, negligible.

constexpr int BLOCK = 256;
constexpr int ROWS_PER_BLOCK = 32;

// Native clang vector type: __builtin_nontemporal_store rejects HIP's
// float4 class type but accepts ext_vector_type.
typedef float floatx4 __attribute__((ext_vector_type(4)));

__global__ __launch_bounds__(BLOCK) void bspline_fill_kernel(
    const float* __restrict__ xs,
    const float* __restrict__ B,   // [4][4] ascending-power coeffs
    float* __restrict__ out,
    int n_samples,
    int n_knots) {
    const int tid = threadIdx.x;
    const int base_row = blockIdx.x * ROWS_PER_BLOCK;
    const int rows = min(ROWS_PER_BLOCK, n_samples - base_row);

    // Prologue: issue the per-row xs loads now; latency hides under Phase A.
    float x = 0.0f;
    if (tid < rows) x = xs[base_row + tid];

    float* chunk = out + (size_t)base_row * (size_t)n_knots;
    const size_t nfloats = (size_t)rows * (size_t)n_knots;

    // ---- Phase A: zero-stream the whole 32-row chunk. No dependence on xs.
    const size_t nvec = nfloats & ~(size_t)3;
    const floatx4 z = {0.0f, 0.0f, 0.0f, 0.0f};
    for (size_t f = (size_t)tid * 4; f < nvec; f += (size_t)BLOCK * 4) {
        __builtin_nontemporal_store(z, (floatx4*)(chunk + f));
    }
    // Scalar tail (n_knots % 4 != 0; not hit for n=2048).
    for (size_t f = nvec + (size_t)tid; f < nfloats; f += (size_t)BLOCK) {
        chunk[f] = 0.0f;
    }

    // __syncthreads on gfx950 drains vmcnt before s_barrier: all zero-writes
    // reach the coherency point before any Phase-B overwrite issues.
    __syncthreads();

    // ---- Phase B: one thread per row writes the 4 nonzero cubic values.
    if (tid < rows) {
        const float fif = floorf(x);
        const int fi = (int)fif;
        const float frac = x - fif;
        float t, v0, v1, v2, v3;
        t = frac + 3.0f; v0 = ((B[ 3]*t + B[ 2])*t + B[ 1])*t + B[ 0];
        t = frac + 2.0f; v1 = ((B[ 7]*t + B[ 6])*t + B[ 5])*t + B[ 4];
        t = frac + 1.0f; v2 = ((B[11]*t + B[10])*t + B[ 9])*t + B[ 8];
        t = frac;        v3 = ((B[15]*t + B[14])*t + B[13])*t + B[12];
        const float vals[4] = {v0, v1, v2, v3};
        float* rowp = chunk + (size_t)tid * (size_t)n_knots;
        #pragma unroll
        for (int k = 0; k < 4; ++k) {
            const int c = fi + k;
            if (c >= 0 && c < n_knots) rowp[c] = vals[k];
        }
    }
}

extern "C" void kernel_launch(void* const* d_in, const int* in_sizes, int n_in,
                              void* d_out, int out_size, void* d_ws, size_t ws_size,
                              hipStream_t stream) {
    const float* xs = (const float*)d_in[0];
    const float* B  = (const float*)d_in[1];   // 16 floats (q=3)
    float* out = (float*)d_out;

    const int n_samples = in_sizes[0];                 // 131072
    const int n_knots   = out_size / n_samples;        // 2048

    const int grid = (n_samples + ROWS_PER_BLOCK - 1) / ROWS_PER_BLOCK;
    bspline_fill_kernel<<<grid, BLOCK, 0, stream>>>(xs, B, out, n_samples, n_knots);
}